// Round 13
// baseline (69.753 us; speedup 1.0000x reference)
//
#include <hip/hip_runtime.h>
#include <cstdint>

#define BB 2
#define LL 2048
#define DD 1024
#define NN 16
#define CC 128     // chunks per sequence
#define SS 16      // steps per chunk
#define PB 8       // proj rows per block (2 rows/thread, wave = 2 rows)

// ---------------------------------------------------------------------------
// Kernel 1: projections with W staged in LDS, W-MAJOR layout (bank-conflict
// free): w4[w*128 + k4]. Reads: lane l -> w4[w*128 + l] / w4[w*128+64+l],
// 64 lanes span 1024B contiguous (canonical conflict-free ds_read_b128).
// Staging: thread f writes w4[f] (contiguous). VMEM traffic: 33 W float4
// loads/thread (4x less than R9's direct-L1 path).
// out[4096,33] = seq @ [W_B(16); W_C(16); W_Delta]^T; block 256 = 4 waves,
// wave wi owns rows {bid*8 + 2wi, +1}; R9-verbatim epilogue via union.
// ---------------------------------------------------------------------------
union ProjLDS {
    float4 w4[4224];          // [w 33][k4 128] per half (67.6 KB)
    float  red[2 * 256 * 34]; // epilogue (69.6 KB) -> union = 69.6 KB
};

__global__ __launch_bounds__(256) void k_proj(
    const float* __restrict__ seq,
    const float* __restrict__ W_B, const float* __restrict__ b_B,
    const float* __restrict__ W_C, const float* __restrict__ b_C,
    const float* __restrict__ W_D, const float* __restrict__ b_D,
    const float* __restrict__ bias_D,
    float* __restrict__ Bm, float* __restrict__ Cm, float* __restrict__ Dl)
{
    __shared__ ProjLDS u;

    const int tid  = threadIdx.x;
    const int wi   = tid >> 6;            // wave 0..3
    const int lane = tid & 63;
    const int row0 = blockIdx.x * PB + wi * 2;

    // Prefetch seq fragments: 2 rows x 2 halves x 2 k4-slots (8 float4).
    float4 sv[2][2][2];
    #pragma unroll
    for (int r = 0; r < 2; ++r) {
        const float* sr = seq + (size_t)(row0 + r) * DD;
        #pragma unroll
        for (int h = 0; h < 2; ++h) {
            #pragma unroll
            for (int j = 0; j < 2; ++j)
                sv[r][h][j] = *(const float4*)&sr[h * 512 + j * 256 + lane * 4];
        }
    }

    float pb[2][16], pc[2][16], pd[2];
    #pragma unroll
    for (int w = 0; w < 16; ++w) { pb[0][w]=0.f; pb[1][w]=0.f; pc[0][w]=0.f; pc[1][w]=0.f; }
    pd[0] = 0.f; pd[1] = 0.f;

    #pragma unroll
    for (int h = 0; h < 2; ++h) {
        __syncthreads();                  // prior half's reads complete
        // Stage W[:, h*512:(h+1)*512]: 4224 float4; thread f -> w4[f]
        // (w = f>>7, k4 = f&127). Contiguous LDS writes, coalesced L2 reads.
        #pragma unroll
        for (int i = 0; i < 17; ++i) {
            int f = tid + i * 256;
            if (f < 4224) {
                int w  = f >> 7;
                int k4 = f & 127;
                const float* wsrc = (w < 16) ? (W_B + (size_t)w * DD)
                                  : (w < 32) ? (W_C + (size_t)(w - 16) * DD)
                                             : W_D;
                u.w4[f] = *(const float4*)&wsrc[h * 512 + k4 * 4];
            }
        }
        __syncthreads();

        // Compute: per w, 2 contiguous (conflict-free) b128 reads, 16 FMAs.
        #pragma unroll
        for (int w = 0; w < 33; ++w) {
            float4 wa = u.w4[w * 128 + lane];        // k4 = lane
            float4 wb = u.w4[w * 128 + 64 + lane];   // k4 = lane + 64
            #pragma unroll
            for (int r = 0; r < 2; ++r) {
                float a = (w < 16) ? pb[r][w & 15]
                        : (w < 32) ? pc[r][w & 15] : pd[r];
                a = fmaf(sv[r][h][0].x, wa.x, a); a = fmaf(sv[r][h][0].y, wa.y, a);
                a = fmaf(sv[r][h][0].z, wa.z, a); a = fmaf(sv[r][h][0].w, wa.w, a);
                a = fmaf(sv[r][h][1].x, wb.x, a); a = fmaf(sv[r][h][1].y, wb.y, a);
                a = fmaf(sv[r][h][1].z, wb.z, a); a = fmaf(sv[r][h][1].w, wb.w, a);
                if (w < 16)      pb[r][w & 15] = a;
                else if (w < 32) pc[r][w & 15] = a;
                else             pd[r] = a;
            }
        }
    }

    // Epilogue (R9-verbatim, via union).
    __syncthreads();                      // all w4 reads done before overwrite
    float* m0 = &u.red[tid * 34];         // row 2*wi
    float* m1 = &u.red[(256 + tid) * 34]; // row 2*wi+1
    #pragma unroll
    for (int w = 0; w < 16; ++w) { m0[w] = pb[0][w]; m1[w] = pb[1][w]; }
    #pragma unroll
    for (int w = 0; w < 16; ++w) { m0[16+w] = pc[0][w]; m1[16+w] = pc[1][w]; }
    m0[32] = pd[0]; m1[32] = pd[1];
    __syncthreads();

    for (int t = tid; t < PB * 33; t += 256) {
        int row_o = t / 33;
        int w_o   = t - row_o * 33;
        const float* base = &u.red[((row_o & 1) * 256 + (row_o >> 1) * 64) * 34 + w_o];
        float s = 0.f;
        #pragma unroll
        for (int k = 0; k < 64; ++k) s += base[k * 34];
        int rg = blockIdx.x * PB + row_o;
        if (w_o < 16) {
            Bm[(size_t)rg * NN + w_o] = s + b_B[w_o];
        } else if (w_o < 32) {
            Cm[(size_t)rg * NN + (w_o - 16)] = s + b_C[w_o - 16];
        } else {
            float z = s + b_D[0] + bias_D[0];
            Dl[rg] = (z > 15.f) ? z : log1pf(__expf(z));
        }
    }
}

// ---------------------------------------------------------------------------
// Kernel 2: per-chunk local scan (verified R6/R9, unchanged).
// ---------------------------------------------------------------------------
__global__ __launch_bounds__(256) void k_scan_local(
    const float* __restrict__ seq, const float* __restrict__ A,
    const float* __restrict__ Dl, const float* __restrict__ Bm,
    float* __restrict__ Gp, float* __restrict__ Sl)
{
    __shared__ float  dlds[SS];
    __shared__ float4 blds[SS * 4];

    const int t = threadIdx.x;
    const int d = ((blockIdx.x & 3) << 8) | t;
    const int b = (blockIdx.x >> 2) & 1;
    const int c = blockIdx.x >> 3;
    const int l0 = c * SS;

    const float4* bp = (const float4*)(Bm + ((size_t)b * LL + l0) * NN);
    if (t < SS * 4)            blds[t]          = bp[t];
    else if (t < SS * 4 + SS)  dlds[t - SS * 4] = Dl[(size_t)b * LL + l0 + (t - SS * 4)];

    const float A_d  = A[(size_t)d * NN];
    const float invA = 1.0f / A_d;

    const float* xp = seq + ((size_t)b * LL + l0) * DD + d;
    float x16[SS];
    #pragma unroll
    for (int i = 0; i < SS; ++i) x16[i] = xp[(size_t)i * DD];

    float st[NN];
    #pragma unroll
    for (int n = 0; n < NN; ++n) st[n] = 0.f;
    float g = 1.f;

    __syncthreads();

    #pragma unroll
    for (int r = 0; r < SS; ++r) {
        float  delta = dlds[r];
        float4 b0 = blds[r*4+0], b1 = blds[r*4+1], b2 = blds[r*4+2], b3 = blds[r*4+3];
        float abar = __expf(A_d * delta);
        float u    = (abar - 1.f) * invA * x16[r];
        float bm[NN] = { b0.x,b0.y,b0.z,b0.w, b1.x,b1.y,b1.z,b1.w,
                         b2.x,b2.y,b2.z,b2.w, b3.x,b3.y,b3.z,b3.w };
        #pragma unroll
        for (int n = 0; n < NN; ++n) st[n] = fmaf(st[n], abar, u * bm[n]);
        g *= abar;
    }

    Gp[((size_t)b * CC + c) * DD + d] = g;
    float4* so = (float4*)(Sl + (((size_t)b * CC + c) * DD + d) * NN);
    so[0] = make_float4(st[0],  st[1],  st[2],  st[3]);
    so[1] = make_float4(st[4],  st[5],  st[6],  st[7]);
    so[2] = make_float4(st[8],  st[9],  st[10], st[11]);
    so[3] = make_float4(st[12], st[13], st[14], st[15]);
}

// ---------------------------------------------------------------------------
// Kernel 3: prefix over chunks via LDS Hillis-Steele (verified R6/R9).
// ---------------------------------------------------------------------------
__global__ __launch_bounds__(256) void k_prefix(
    float* __restrict__ Sl, const float* __restrict__ Gp)
{
    __shared__ float sA[CC * 16], sB[CC * 16];
    __shared__ float gA[CC], gB[CC];

    const int t = threadIdx.x;
    const int d = blockIdx.x & (DD - 1);
    const int b = blockIdx.x >> 10;

    for (int i = 0; i < 8; ++i) {
        const int e = i * 256 + t;
        const int c = e >> 4, n = e & 15;
        sA[e] = Sl[(((size_t)b * CC + c) * DD + d) * NN + n];
    }
    if (t < CC) gA[t] = Gp[((size_t)b * CC + t) * DD + d];
    __syncthreads();

    float* curS = sA; float* nxtS = sB;
    float* curG = gA; float* nxtG = gB;
    for (int dk = 1; dk < CC; dk <<= 1) {
        for (int i = 0; i < 8; ++i) {
            const int e = i * 256 + t;
            const int c = e >> 4;
            float s = curS[e];
            if (c >= dk) s = fmaf(curG[c], curS[e - (dk << 4)], s);
            nxtS[e] = s;
        }
        if (t < CC) {
            float g = curG[t];
            if (t >= dk) g *= curG[t - dk];
            nxtG[t] = g;
        }
        __syncthreads();
        float* tp = curS; curS = nxtS; nxtS = tp;
        tp = curG; curG = nxtG; nxtG = tp;
    }

    for (int i = 0; i < 8; ++i) {
        const int e = i * 256 + t;
        const int c = e >> 4, n = e & 15;
        Sl[(((size_t)b * CC + c) * DD + d) * NN + n] = curS[e];
    }
}

// ---------------------------------------------------------------------------
// Kernel 4: final scan seeded with prefix state; emits y (verified R6/R9).
// ---------------------------------------------------------------------------
__global__ __launch_bounds__(256) void k_scan_out(
    const float* __restrict__ seq, const float* __restrict__ A,
    const float* __restrict__ Dl, const float* __restrict__ Bm,
    const float* __restrict__ Cm, const float* __restrict__ Sl,
    float* __restrict__ out)
{
    __shared__ float  dlds[SS];
    __shared__ float4 blds[SS * 4];
    __shared__ float4 clds[SS * 4];

    const int t = threadIdx.x;
    const int d = ((blockIdx.x & 3) << 8) | t;
    const int b = (blockIdx.x >> 2) & 1;
    const int c = blockIdx.x >> 3;
    const int l0 = c * SS;

    const float4* bp = (const float4*)(Bm + ((size_t)b * LL + l0) * NN);
    const float4* cp = (const float4*)(Cm + ((size_t)b * LL + l0) * NN);
    if (t < SS * 4)            blds[t]          = bp[t];
    else if (t < SS * 8)       clds[t - SS * 4] = cp[t - SS * 4];
    else if (t < SS * 8 + SS)  dlds[t - SS * 8] = Dl[(size_t)b * LL + l0 + (t - SS * 8)];

    const float A_d  = A[(size_t)d * NN];
    const float invA = 1.0f / A_d;

    const float* xp = seq + ((size_t)b * LL + l0) * DD + d;
    float x16[SS];
    #pragma unroll
    for (int i = 0; i < SS; ++i) x16[i] = xp[(size_t)i * DD];

    float st[NN];
    if (c == 0) {
        #pragma unroll
        for (int n = 0; n < NN; ++n) st[n] = 0.f;
    } else {
        const float4* si = (const float4*)(
            Sl + (((size_t)b * CC + (c - 1)) * DD + d) * NN);
        float4 v0 = si[0], v1 = si[1], v2 = si[2], v3 = si[3];
        st[0]=v0.x; st[1]=v0.y; st[2]=v0.z; st[3]=v0.w;
        st[4]=v1.x; st[5]=v1.y; st[6]=v1.z; st[7]=v1.w;
        st[8]=v2.x; st[9]=v2.y; st[10]=v2.z; st[11]=v2.w;
        st[12]=v3.x; st[13]=v3.y; st[14]=v3.z; st[15]=v3.w;
    }

    float* yp = out + ((size_t)b * LL + l0) * DD + d;
    __syncthreads();

    #pragma unroll
    for (int r = 0; r < SS; ++r) {
        float  delta = dlds[r];
        float4 b0 = blds[r*4+0], b1 = blds[r*4+1], b2 = blds[r*4+2], b3 = blds[r*4+3];
        float abar = __expf(A_d * delta);
        float u    = (abar - 1.f) * invA * x16[r];
        float bm[NN] = { b0.x,b0.y,b0.z,b0.w, b1.x,b1.y,b1.z,b1.w,
                         b2.x,b2.y,b2.z,b2.w, b3.x,b3.y,b3.z,b3.w };
        #pragma unroll
        for (int n = 0; n < NN; ++n) st[n] = fmaf(st[n], abar, u * bm[n]);

        float4 c0 = clds[r*4+0], c1 = clds[r*4+1], c2 = clds[r*4+2], c3 = clds[r*4+3];
        float cm[NN] = { c0.x,c0.y,c0.z,c0.w, c1.x,c1.y,c1.z,c1.w,
                         c2.x,c2.y,c2.z,c2.w, c3.x,c3.y,c3.z,c3.w };
        float y0 = 0.f, y1 = 0.f, y2 = 0.f, y3 = 0.f;
        #pragma unroll
        for (int n = 0; n < NN; n += 4) {
            y0 = fmaf(st[n+0], cm[n+0], y0);
            y1 = fmaf(st[n+1], cm[n+1], y1);
            y2 = fmaf(st[n+2], cm[n+2], y2);
            y3 = fmaf(st[n+3], cm[n+3], y3);
        }
        yp[(size_t)r * DD] = (y0 + y1) + (y2 + y3);
    }
}

extern "C" void kernel_launch(void* const* d_in, const int* in_sizes, int n_in,
                              void* d_out, int out_size, void* d_ws, size_t ws_size,
                              hipStream_t stream)
{
    const float* seq    = (const float*)d_in[0];
    const float* A      = (const float*)d_in[1];
    const float* W_B    = (const float*)d_in[2];
    const float* b_B    = (const float*)d_in[3];
    const float* W_C    = (const float*)d_in[4];
    const float* b_C    = (const float*)d_in[5];
    const float* W_D    = (const float*)d_in[6];
    const float* b_D    = (const float*)d_in[7];
    const float* bias_D = (const float*)d_in[8];
    float* out = (float*)d_out;
    float* ws  = (float*)d_ws;

    // Workspace (floats): Bm(B*L*N) Cm(B*L*N) Dl(B*L) Gp(B*CC*D) Sl(B*CC*D*N)
    float* Bm = ws;
    float* Cm = Bm + (size_t)BB * LL * NN;
    float* Dl = Cm + (size_t)BB * LL * NN;
    float* Gp = Dl + (size_t)BB * LL;
    float* Sl = Gp + (size_t)BB * CC * DD;   // total ~18.9 MB

    k_proj<<<(BB * LL) / PB, 256, 0, stream>>>(seq, W_B, b_B, W_C, b_C,
                                               W_D, b_D, bias_D, Bm, Cm, Dl);
    k_scan_local<<<(BB * DD * CC) / 256, 256, 0, stream>>>(seq, A, Dl, Bm, Gp, Sl);
    k_prefix<<<BB * DD, 256, 0, stream>>>(Sl, Gp);
    k_scan_out<<<(BB * DD * CC) / 256, 256, 0, stream>>>(seq, A, Dl, Bm, Cm, Sl, out);
}

// Round 14
// 61.374 us; speedup vs baseline: 1.1365x; 1.1365x over previous
//
#include <hip/hip_runtime.h>
#include <cstdint>

#define BB 2
#define LL 2048
#define DD 1024
#define NN 16
#define CC 128     // chunks per sequence
#define SS 16      // steps per chunk
#define PB 8       // proj rows per block (2 rows per thread)

// ---------------------------------------------------------------------------
// Kernel 1: projections, register-resident, 2 rows/thread (R9-verbatim, the
// best of 6 measured proj designs: 13us. Keeps 8 waves/CU AND 8:1 FMA:load).
// out[4096,33] = seq[4096,1024] @ W^T,  W rows = [W_B(16); W_C(16); W_Delta].
// Block = 256 threads, 8 rows/block, grid = 512 (2 blocks/CU).
// Thread (r2 = tid>>6 -> rows {2*r2, 2*r2+1}, ks = tid&63) owns K cols
// {q*256 + ks*4 .. +3, q<4} (16 floats per row). Each W float4 load feeds
// 32 FMAs (2 rows x 16). LDS pad-34 epilogue reduction.
// ---------------------------------------------------------------------------
__global__ __launch_bounds__(256) void k_proj(
    const float* __restrict__ seq,
    const float* __restrict__ W_B, const float* __restrict__ b_B,
    const float* __restrict__ W_C, const float* __restrict__ b_C,
    const float* __restrict__ W_D, const float* __restrict__ b_D,
    const float* __restrict__ bias_D,
    float* __restrict__ Bm, float* __restrict__ Cm, float* __restrict__ Dl)
{
    __shared__ float red[2 * 256 * 34];   // [rowpair(2)][thread 256][w 34]

    const int tid = threadIdx.x;
    const int r2  = tid >> 6;             // 0..3 -> rows 2*r2, 2*r2+1
    const int ks  = tid & 63;             // 0..63
    const int row0 = blockIdx.x * PB + r2 * 2;

    const float* s0 = seq + (size_t)row0 * DD;
    const float* s1 = seq + (size_t)(row0 + 1) * DD;
    float4 sv0[4], sv1[4];
    #pragma unroll
    for (int q = 0; q < 4; ++q) {
        sv0[q] = *(const float4*)&s0[q * 256 + ks * 4];
        sv1[q] = *(const float4*)&s1[q * 256 + ks * 4];
    }

    float pb0[16], pb1[16], pc0[16], pc1[16], pd0, pd1;

    #pragma unroll
    for (int w = 0; w < 16; ++w) {
        const float* wr = W_B + (size_t)w * DD;
        float a0 = 0.f, a1 = 0.f;
        #pragma unroll
        for (int q = 0; q < 4; ++q) {
            float4 wv = *(const float4*)&wr[q * 256 + ks * 4];
            a0 = fmaf(sv0[q].x, wv.x, a0); a0 = fmaf(sv0[q].y, wv.y, a0);
            a0 = fmaf(sv0[q].z, wv.z, a0); a0 = fmaf(sv0[q].w, wv.w, a0);
            a1 = fmaf(sv1[q].x, wv.x, a1); a1 = fmaf(sv1[q].y, wv.y, a1);
            a1 = fmaf(sv1[q].z, wv.z, a1); a1 = fmaf(sv1[q].w, wv.w, a1);
        }
        pb0[w] = a0; pb1[w] = a1;
    }
    #pragma unroll
    for (int w = 0; w < 16; ++w) {
        const float* wr = W_C + (size_t)w * DD;
        float a0 = 0.f, a1 = 0.f;
        #pragma unroll
        for (int q = 0; q < 4; ++q) {
            float4 wv = *(const float4*)&wr[q * 256 + ks * 4];
            a0 = fmaf(sv0[q].x, wv.x, a0); a0 = fmaf(sv0[q].y, wv.y, a0);
            a0 = fmaf(sv0[q].z, wv.z, a0); a0 = fmaf(sv0[q].w, wv.w, a0);
            a1 = fmaf(sv1[q].x, wv.x, a1); a1 = fmaf(sv1[q].y, wv.y, a1);
            a1 = fmaf(sv1[q].z, wv.z, a1); a1 = fmaf(sv1[q].w, wv.w, a1);
        }
        pc0[w] = a0; pc1[w] = a1;
    }
    {
        float a0 = 0.f, a1 = 0.f;
        #pragma unroll
        for (int q = 0; q < 4; ++q) {
            float4 wv = *(const float4*)&W_D[q * 256 + ks * 4];
            a0 = fmaf(sv0[q].x, wv.x, a0); a0 = fmaf(sv0[q].y, wv.y, a0);
            a0 = fmaf(sv0[q].z, wv.z, a0); a0 = fmaf(sv0[q].w, wv.w, a0);
            a1 = fmaf(sv1[q].x, wv.x, a1); a1 = fmaf(sv1[q].y, wv.y, a1);
            a1 = fmaf(sv1[q].z, wv.z, a1); a1 = fmaf(sv1[q].w, wv.w, a1);
        }
        pd0 = a0; pd1 = a1;
    }

    float* m0 = &red[tid * 34];                 // row 2*r2
    float* m1 = &red[(256 + tid) * 34];         // row 2*r2+1
    #pragma unroll
    for (int w = 0; w < 16; ++w) { m0[w] = pb0[w]; m1[w] = pb1[w]; }
    #pragma unroll
    for (int w = 0; w < 16; ++w) { m0[16+w] = pc0[w]; m1[16+w] = pc1[w]; }
    m0[32] = pd0; m1[32] = pd1;
    __syncthreads();

    // Epilogue: 8 rows x 33 outputs = 264. Output t: row_o = t/33, w_o = t%33.
    // Row row_o lives at red[half][(r2= row_o>>1)*64 + k][w], half = row_o&1.
    for (int t = tid; t < PB * 33; t += 256) {
        int row_o = t / 33;
        int w_o   = t - row_o * 33;
        const float* base = &red[((row_o & 1) * 256 + (row_o >> 1) * 64) * 34 + w_o];
        float s = 0.f;
        #pragma unroll
        for (int k = 0; k < 64; ++k) s += base[k * 34];
        int rg = blockIdx.x * PB + row_o;
        if (w_o < 16) {
            Bm[(size_t)rg * NN + w_o] = s + b_B[w_o];
        } else if (w_o < 32) {
            Cm[(size_t)rg * NN + (w_o - 16)] = s + b_C[w_o - 16];
        } else {
            float z = s + b_D[0] + bias_D[0];
            Dl[rg] = (z > 15.f) ? z : log1pf(__expf(z));
        }
    }
}

// ---------------------------------------------------------------------------
// Kernel 2: per-chunk local scan (verified R6/R9).
// ---------------------------------------------------------------------------
__global__ __launch_bounds__(256) void k_scan_local(
    const float* __restrict__ seq, const float* __restrict__ A,
    const float* __restrict__ Dl, const float* __restrict__ Bm,
    float* __restrict__ Gp, float* __restrict__ Sl)
{
    __shared__ float  dlds[SS];
    __shared__ float4 blds[SS * 4];

    const int t = threadIdx.x;
    const int d = ((blockIdx.x & 3) << 8) | t;
    const int b = (blockIdx.x >> 2) & 1;
    const int c = blockIdx.x >> 3;
    const int l0 = c * SS;

    const float4* bp = (const float4*)(Bm + ((size_t)b * LL + l0) * NN);
    if (t < SS * 4)            blds[t]          = bp[t];
    else if (t < SS * 4 + SS)  dlds[t - SS * 4] = Dl[(size_t)b * LL + l0 + (t - SS * 4)];

    const float A_d  = A[(size_t)d * NN];
    const float invA = 1.0f / A_d;

    const float* xp = seq + ((size_t)b * LL + l0) * DD + d;
    float x16[SS];
    #pragma unroll
    for (int i = 0; i < SS; ++i) x16[i] = xp[(size_t)i * DD];

    float st[NN];
    #pragma unroll
    for (int n = 0; n < NN; ++n) st[n] = 0.f;
    float g = 1.f;

    __syncthreads();

    #pragma unroll
    for (int r = 0; r < SS; ++r) {
        float  delta = dlds[r];
        float4 b0 = blds[r*4+0], b1 = blds[r*4+1], b2 = blds[r*4+2], b3 = blds[r*4+3];
        float abar = __expf(A_d * delta);
        float u    = (abar - 1.f) * invA * x16[r];
        float bm[NN] = { b0.x,b0.y,b0.z,b0.w, b1.x,b1.y,b1.z,b1.w,
                         b2.x,b2.y,b2.z,b2.w, b3.x,b3.y,b3.z,b3.w };
        #pragma unroll
        for (int n = 0; n < NN; ++n) st[n] = fmaf(st[n], abar, u * bm[n]);
        g *= abar;
    }

    Gp[((size_t)b * CC + c) * DD + d] = g;
    float4* so = (float4*)(Sl + (((size_t)b * CC + c) * DD + d) * NN);
    so[0] = make_float4(st[0],  st[1],  st[2],  st[3]);
    so[1] = make_float4(st[4],  st[5],  st[6],  st[7]);
    so[2] = make_float4(st[8],  st[9],  st[10], st[11]);
    so[3] = make_float4(st[12], st[13], st[14], st[15]);
}

// ---------------------------------------------------------------------------
// Kernel 3: prefix over chunks via LDS Hillis-Steele (verified R6/R9).
// ---------------------------------------------------------------------------
__global__ __launch_bounds__(256) void k_prefix(
    float* __restrict__ Sl, const float* __restrict__ Gp)
{
    __shared__ float sA[CC * 16], sB[CC * 16];
    __shared__ float gA[CC], gB[CC];

    const int t = threadIdx.x;
    const int d = blockIdx.x & (DD - 1);
    const int b = blockIdx.x >> 10;

    for (int i = 0; i < 8; ++i) {
        const int e = i * 256 + t;
        const int c = e >> 4, n = e & 15;
        sA[e] = Sl[(((size_t)b * CC + c) * DD + d) * NN + n];
    }
    if (t < CC) gA[t] = Gp[((size_t)b * CC + t) * DD + d];
    __syncthreads();

    float* curS = sA; float* nxtS = sB;
    float* curG = gA; float* nxtG = gB;
    for (int dk = 1; dk < CC; dk <<= 1) {
        for (int i = 0; i < 8; ++i) {
            const int e = i * 256 + t;
            const int c = e >> 4;
            float s = curS[e];
            if (c >= dk) s = fmaf(curG[c], curS[e - (dk << 4)], s);
            nxtS[e] = s;
        }
        if (t < CC) {
            float g = curG[t];
            if (t >= dk) g *= curG[t - dk];
            nxtG[t] = g;
        }
        __syncthreads();
        float* tp = curS; curS = nxtS; nxtS = tp;
        tp = curG; curG = nxtG; nxtG = tp;
    }

    for (int i = 0; i < 8; ++i) {
        const int e = i * 256 + t;
        const int c = e >> 4, n = e & 15;
        Sl[(((size_t)b * CC + c) * DD + d) * NN + n] = curS[e];
    }
}

// ---------------------------------------------------------------------------
// Kernel 4: final scan seeded with prefix state; emits y (verified R6/R9).
// ---------------------------------------------------------------------------
__global__ __launch_bounds__(256) void k_scan_out(
    const float* __restrict__ seq, const float* __restrict__ A,
    const float* __restrict__ Dl, const float* __restrict__ Bm,
    const float* __restrict__ Cm, const float* __restrict__ Sl,
    float* __restrict__ out)
{
    __shared__ float  dlds[SS];
    __shared__ float4 blds[SS * 4];
    __shared__ float4 clds[SS * 4];

    const int t = threadIdx.x;
    const int d = ((blockIdx.x & 3) << 8) | t;
    const int b = (blockIdx.x >> 2) & 1;
    const int c = blockIdx.x >> 3;
    const int l0 = c * SS;

    const float4* bp = (const float4*)(Bm + ((size_t)b * LL + l0) * NN);
    const float4* cp = (const float4*)(Cm + ((size_t)b * LL + l0) * NN);
    if (t < SS * 4)            blds[t]          = bp[t];
    else if (t < SS * 8)       clds[t - SS * 4] = cp[t - SS * 4];
    else if (t < SS * 8 + SS)  dlds[t - SS * 8] = Dl[(size_t)b * LL + l0 + (t - SS * 8)];

    const float A_d  = A[(size_t)d * NN];
    const float invA = 1.0f / A_d;

    const float* xp = seq + ((size_t)b * LL + l0) * DD + d;
    float x16[SS];
    #pragma unroll
    for (int i = 0; i < SS; ++i) x16[i] = xp[(size_t)i * DD];

    float st[NN];
    if (c == 0) {
        #pragma unroll
        for (int n = 0; n < NN; ++n) st[n] = 0.f;
    } else {
        const float4* si = (const float4*)(
            Sl + (((size_t)b * CC + (c - 1)) * DD + d) * NN);
        float4 v0 = si[0], v1 = si[1], v2 = si[2], v3 = si[3];
        st[0]=v0.x; st[1]=v0.y; st[2]=v0.z; st[3]=v0.w;
        st[4]=v1.x; st[5]=v1.y; st[6]=v1.z; st[7]=v1.w;
        st[8]=v2.x; st[9]=v2.y; st[10]=v2.z; st[11]=v2.w;
        st[12]=v3.x; st[13]=v3.y; st[14]=v3.z; st[15]=v3.w;
    }

    float* yp = out + ((size_t)b * LL + l0) * DD + d;
    __syncthreads();

    #pragma unroll
    for (int r = 0; r < SS; ++r) {
        float  delta = dlds[r];
        float4 b0 = blds[r*4+0], b1 = blds[r*4+1], b2 = blds[r*4+2], b3 = blds[r*4+3];
        float abar = __expf(A_d * delta);
        float u    = (abar - 1.f) * invA * x16[r];
        float bm[NN] = { b0.x,b0.y,b0.z,b0.w, b1.x,b1.y,b1.z,b1.w,
                         b2.x,b2.y,b2.z,b2.w, b3.x,b3.y,b3.z,b3.w };
        #pragma unroll
        for (int n = 0; n < NN; ++n) st[n] = fmaf(st[n], abar, u * bm[n]);

        float4 c0 = clds[r*4+0], c1 = clds[r*4+1], c2 = clds[r*4+2], c3 = clds[r*4+3];
        float cm[NN] = { c0.x,c0.y,c0.z,c0.w, c1.x,c1.y,c1.z,c1.w,
                         c2.x,c2.y,c2.z,c2.w, c3.x,c3.y,c3.z,c3.w };
        float y0 = 0.f, y1 = 0.f, y2 = 0.f, y3 = 0.f;
        #pragma unroll
        for (int n = 0; n < NN; n += 4) {
            y0 = fmaf(st[n+0], cm[n+0], y0);
            y1 = fmaf(st[n+1], cm[n+1], y1);
            y2 = fmaf(st[n+2], cm[n+2], y2);
            y3 = fmaf(st[n+3], cm[n+3], y3);
        }
        yp[(size_t)r * DD] = (y0 + y1) + (y2 + y3);
    }
}

extern "C" void kernel_launch(void* const* d_in, const int* in_sizes, int n_in,
                              void* d_out, int out_size, void* d_ws, size_t ws_size,
                              hipStream_t stream)
{
    const float* seq    = (const float*)d_in[0];
    const float* A      = (const float*)d_in[1];
    const float* W_B    = (const float*)d_in[2];
    const float* b_B    = (const float*)d_in[3];
    const float* W_C    = (const float*)d_in[4];
    const float* b_C    = (const float*)d_in[5];
    const float* W_D    = (const float*)d_in[6];
    const float* b_D    = (const float*)d_in[7];
    const float* bias_D = (const float*)d_in[8];
    float* out = (float*)d_out;
    float* ws  = (float*)d_ws;

    // Workspace (floats): Bm(B*L*N) Cm(B*L*N) Dl(B*L) Gp(B*CC*D) Sl(B*CC*D*N)
    float* Bm = ws;
    float* Cm = Bm + (size_t)BB * LL * NN;
    float* Dl = Cm + (size_t)BB * LL * NN;
    float* Gp = Dl + (size_t)BB * LL;
    float* Sl = Gp + (size_t)BB * CC * DD;   // total ~18.9 MB

    k_proj<<<(BB * LL) / PB, 256, 0, stream>>>(seq, W_B, b_B, W_C, b_C,
                                               W_D, b_D, bias_D, Bm, Cm, Dl);
    k_scan_local<<<(BB * DD * CC) / 256, 256, 0, stream>>>(seq, A, Dl, Bm, Gp, Sl);
    k_prefix<<<BB * DD, 256, 0, stream>>>(Sl, Gp);
    k_scan_out<<<(BB * DD * CC) / 256, 256, 0, stream>>>(seq, A, Dl, Bm, Cm, Sl, out);
}